// Round 2
// baseline (12373.912 us; speedup 1.0000x reference)
//
#include <hip/hip_runtime.h>
#include <hip/hip_fp16.h>

#define LL 5
#define H 1024
#define G 4096   // 4*H
#define T 128
#define BS 512
#define BSH (BS * H)
#define BSG (BS * G)
#define GH  (G * H)

typedef _Float16 f16x8 __attribute__((ext_vector_type(8)));
typedef float f32x4 __attribute__((ext_vector_type(4)));

__device__ __forceinline__ float sigmoidf_(float x) { return 1.f / (1.f + __expf(-x)); }
__device__ __forceinline__ float tanhf_(float x) { return 2.f / (1.f + __expf(-2.f * x)) - 1.f; }

// async 16B global->LDS (DMA, no VGPR roundtrip). LDS dest = wave-uniform base + lane*16.
__device__ __forceinline__ void gll16(const void* g, void* l) {
  __builtin_amdgcn_global_load_lds(
      (const __attribute__((address_space(1))) void*)g,
      (__attribute__((address_space(3))) void*)l, 16, 0, 0);
}

// ================= prelude kernels =================

__global__ void k_convert(const float* __restrict__ Whf, const float* __restrict__ Wxf,
                          __half* __restrict__ Whb, __half* __restrict__ Wxb) {
  const long long n1 = (long long)LL * GH / 4;
  const long long n2 = (long long)(LL - 1) * GH / 4;
  long long i = (long long)blockIdx.x * blockDim.x + threadIdx.x;
  long long stride = (long long)gridDim.x * blockDim.x;
  for (long long v = i; v < n1 + n2; v += stride) {
    const float4* src; __half* dst; long long idx;
    if (v < n1) { src = (const float4*)Whf; dst = Whb; idx = v; }
    else        { src = (const float4*)Wxf; dst = Wxb; idx = v - n1; }
    float4 f = src[idx];
    ushort4 u;
    u.x = __half_as_ushort(__float2half(f.x));
    u.y = __half_as_ushort(__float2half(f.y));
    u.z = __half_as_ushort(__float2half(f.z));
    u.w = __half_as_ushort(__float2half(f.w));
    ((ushort4*)dst)[idx] = u;
  }
}

__global__ void k_bias_y(const float* __restrict__ bih, const float* __restrict__ bhh,
                         float* __restrict__ bias, float* __restrict__ y0,
                         float* __restrict__ y1) {
  int i = blockIdx.x * blockDim.x + threadIdx.x;
  if (i < LL * G) bias[i] = bih[i] + bhh[i];
  if (i < BS) { y0[i] = 0.f; y1[i] = 0.f; }
}

__global__ void k_init(const float* __restrict__ x, __half* __restrict__ hbuf,
                       float* __restrict__ c) {
  int i = blockIdx.x * blockDim.x + threadIdx.x;
  if (i >= BS * H) return;
  float v = x[i];
  __half hb = __float2half(v);
  for (int l = 0; l < LL; l++) {
    hbuf[(long long)l * BSH + i] = hb;
    c[(long long)l * BSH + i] = v;
  }
}

// ================= GEMM core (m97 structure: 128x128 tile, async dbuf, XOR swizzle) ===
// C(128 x 128) = A(128 rows x K=1024) @ W(128 rows x 1024)^T, W rows = 4 gates x 32 j.
// 256 threads = 4 waves (2m x 2n); wave tile 64m x 64n; acc[4][4]; nt == gate.
// LDS: 2 x (A 8192 halfs + B 8192 halfs) = 64 KB. Chunk (16B=8 halfs) at slot
// s within row r holds global chunk s ^ (r&7)  -> frag reads are 2-way max (free).

#define SH_HALFS 32768

__device__ __forceinline__ void stage_tile(const __half* __restrict__ A,
                                           const __half* __restrict__ W,
                                           int m0, int jb, int kb,
                                           __half* aB, __half* bB,
                                           int wave, int lane) {
  const int i8 = lane >> 3;          // row within 8-row group
  const int j8 = lane & 7;           // LDS slot chunk within row
  const int kch = j8 ^ i8;           // swizzled source chunk
#pragma unroll
  for (int s = 0; s < 4; s++) {      // A: 16 calls of 8 rows, this wave does 4
    int c = wave * 4 + s;
    int row = c * 8 + i8;            // 0..127
    gll16(A + (m0 + row) * H + kb + kch * 8, aB + c * 512);
  }
#pragma unroll
  for (int s = 0; s < 4; s++) {      // B: 16 calls of 8 rows, this wave does 4
    int c = wave * 4 + s;
    int row = c * 8 + i8;                          // 0..127
    int grow = (row >> 5) * H + jb + (row & 31);   // gate*H + j
    gll16(W + grow * H + kb + kch * 8, bB + c * 512);
  }
}

__device__ __forceinline__ void compute_tile(const __half* aB, const __half* bB,
                                             int wave, int lane, f32x4 acc[4][4]) {
  const int quad = lane >> 4, col = lane & 15;
  const int wm = wave >> 1, wn = wave & 1;
  const int sw = col & 7;
#pragma unroll
  for (int ks = 0; ks < 2; ks++) {
    const int kc = ks * 4 + quad;
    const int kcs = kc ^ sw;
    f16x8 af[4], bf[4];
#pragma unroll
    for (int mt = 0; mt < 4; mt++) {
      int r = wm * 64 + mt * 16 + col;
      af[mt] = *(const f16x8*)(aB + ((r << 3) + kcs) * 8);
    }
#pragma unroll
    for (int nt = 0; nt < 4; nt++) {
      int n = nt * 32 + wn * 16 + col;
      bf[nt] = *(const f16x8*)(bB + ((n << 3) + kcs) * 8);
    }
#pragma unroll
    for (int mt = 0; mt < 4; mt++)
#pragma unroll
      for (int nt = 0; nt < 4; nt++)
        acc[mt][nt] = __builtin_amdgcn_mfma_f32_16x16x32_f16(af[mt], bf[nt], acc[mt][nt], 0, 0, 0);
  }
}

__device__ __forceinline__ void gemm_async(const __half* __restrict__ A,
                                           const __half* __restrict__ W,
                                           int m0, int jb, __half* sh, int t,
                                           f32x4 acc[4][4]) {
  const int wave = t >> 6, lane = t & 63;
  stage_tile(A, W, m0, jb, 0, sh, sh + 8192, wave, lane);
  for (int it = 0; it < 16; ++it) {
    __syncthreads();  // drains vmcnt(0): buf[it&1] ready; prev reads of other buf done
    const int cur = it & 1;
    if (it < 15)
      stage_tile(A, W, m0, jb, (it + 1) * 64,
                 sh + (cur ? 0 : 16384), sh + (cur ? 8192 : 24576), wave, lane);
    compute_tile(sh + (cur ? 16384 : 0), sh + (cur ? 24576 : 8192), wave, lane, acc);
  }
}

__device__ __forceinline__ void epilogue_store(f32x4 acc[4][4], __half* __restrict__ Ghout,
                                               const float* __restrict__ biasS,
                                               int m0, int jb, int t) {
  const int lane = t & 63, wave = t >> 6;
  const int quad = lane >> 4, col = lane & 15;
  const int wm = wave >> 1, wn = wave & 1;
  const int j = jb + wn * 16 + col;
  float bs[4];
#pragma unroll
  for (int nt = 0; nt < 4; nt++) bs[nt] = biasS[nt * H + j];
#pragma unroll
  for (int mt = 0; mt < 4; mt++)
#pragma unroll
    for (int nt = 0; nt < 4; nt++)
#pragma unroll
      for (int r = 0; r < 4; r++) {
        int b = m0 + wm * 64 + mt * 16 + quad * 4 + r;
        Ghout[b * G + nt * H + j] = __float2half(acc[mt][nt][r] + bs[nt]);
      }
}

__device__ __forceinline__ void epilogue_cell(f32x4 acc[4][4],
                                              const __half* __restrict__ Ghin,
                                              float* __restrict__ c, __half* __restrict__ hout,
                                              int m0, int jb, int t,
                                              const float* __restrict__ Wro,
                                              float* __restrict__ yAcc, float* red) {
  const int lane = t & 63, wave = t >> 6;
  const int quad = lane >> 4, col = lane & 15;
  const int wm = wave >> 1, wn = wave & 1;
  const int j = jb + wn * 16 + col;
  const float wj = Wro ? Wro[j] : 0.f;
#pragma unroll
  for (int mt = 0; mt < 4; mt++)
#pragma unroll
    for (int r = 0; r < 4; r++) {
      int row = wm * 64 + mt * 16 + quad * 4 + r;
      int b = m0 + row;
      float gi = acc[mt][0][r] + __half2float(Ghin[b * G + j]);
      float gf = acc[mt][1][r] + __half2float(Ghin[b * G + H + j]);
      float gg = acc[mt][2][r] + __half2float(Ghin[b * G + 2 * H + j]);
      float go = acc[mt][3][r] + __half2float(Ghin[b * G + 3 * H + j]);
      float cold = c[b * H + j];
      float cn = sigmoidf_(gf) * cold + sigmoidf_(gi) * tanhf_(gg);
      float hn = sigmoidf_(go) * tanhf_(cn);
      c[b * H + j] = cn;
      hout[b * H + j] = __float2half(hn);
      if (Wro) red[row * 33 + wn * 16 + col] = hn * wj;
    }
  if (Wro) {  // block-level readout reduction: 32 j-columns -> 1 atomic per row
    __syncthreads();
    if (t < 128) {
      float s = 0.f;
#pragma unroll
      for (int k = 0; k < 32; k++) s += red[t * 33 + k];
      atomicAdd(yAcc + m0 + t, s);
    }
  }
}

// ================= main-loop kernels =================

// z=0: x-GEMM + cell for (t,l): A @ Wc + Ghin -> c, hout  (l==4 also: readout into yAcc)
// z=1: h-GEMM: A @ Ws + biasS -> Ghout   (Gh[t+1][l-1])
// z=2 (only l==2 launch): A2 @ Ws2 + bias2 -> Gh2  (Gh[t][4] from h[t-1][4])
__global__ __launch_bounds__(256) void k_dual(
    const __half* __restrict__ A, const __half* __restrict__ Wc,
    const __half* __restrict__ Ws, const __half* __restrict__ Ghin,
    __half* __restrict__ Ghout, const float* __restrict__ biasS,
    float* __restrict__ c_, __half* __restrict__ hout,
    const float* __restrict__ Wro, float* __restrict__ yAcc,
    const __half* __restrict__ A2, const __half* __restrict__ Ws2,
    __half* __restrict__ Gh2, const float* __restrict__ bias2)
{
  __shared__ __half sh[SH_HALFS];
  const int t = threadIdx.x;
  const int jb = blockIdx.x * 32;
  const int m0 = blockIdx.y * 128;
  f32x4 acc[4][4];
#pragma unroll
  for (int a = 0; a < 4; a++)
#pragma unroll
    for (int b = 0; b < 4; b++) acc[a][b] = (f32x4){0.f, 0.f, 0.f, 0.f};
  if (blockIdx.z == 0) {
    gemm_async(A, Wc, m0, jb, sh, t, acc);
    epilogue_cell(acc, Ghin, c_, hout, m0, jb, t, Wro, yAcc, (float*)sh);
  } else if (blockIdx.z == 1) {
    gemm_async(A, Ws, m0, jb, sh, t, acc);
    epilogue_store(acc, Ghout, biasS, m0, jb, t);
  } else {
    gemm_async(A2, Ws2, m0, jb, sh, t, acc);
    epilogue_store(acc, Gh2, bias2, m0, jb, t);
  }
}

// HEAD: pure elementwise layer-0 cell finalize + y bookkeeping (fast chain link)
__global__ __launch_bounds__(256) void k_head(
    const __half* __restrict__ Gh0, const float* __restrict__ W0,
    const float* __restrict__ yA, float* __restrict__ yB,
    const float* __restrict__ bro, float* __restrict__ c0,
    __half* __restrict__ h0, float* __restrict__ out, int tPrev)
{
  int tid = blockIdx.x * 256 + threadIdx.x;   // 128 blocks -> 32768 threads
  for (int e4 = tid; e4 < BS * (H / 4); e4 += 32768) {
    int b = e4 >> 8;
    int j = (e4 & 255) << 2;
    float yv = yA[b];
    const __half2* p;
    p = (const __half2*)(Gh0 + b * G + j);
    float2 i01 = __half22float2(p[0]), i23 = __half22float2(p[1]);
    p = (const __half2*)(Gh0 + b * G + H + j);
    float2 f01 = __half22float2(p[0]), f23 = __half22float2(p[1]);
    p = (const __half2*)(Gh0 + b * G + 2 * H + j);
    float2 g01 = __half22float2(p[0]), g23 = __half22float2(p[1]);
    p = (const __half2*)(Gh0 + b * G + 3 * H + j);
    float2 o01 = __half22float2(p[0]), o23 = __half22float2(p[1]);
    float4 wi = *(const float4*)(W0 + j);
    float4 wf = *(const float4*)(W0 + H + j);
    float4 wg = *(const float4*)(W0 + 2 * H + j);
    float4 wo = *(const float4*)(W0 + 3 * H + j);
    float4 cc = *(const float4*)(c0 + b * H + j);
    float gi[4] = {i01.x + yv * wi.x, i01.y + yv * wi.y, i23.x + yv * wi.z, i23.y + yv * wi.w};
    float gf[4] = {f01.x + yv * wf.x, f01.y + yv * wf.y, f23.x + yv * wf.z, f23.y + yv * wf.w};
    float gg[4] = {g01.x + yv * wg.x, g01.y + yv * wg.y, g23.x + yv * wg.z, g23.y + yv * wg.w};
    float go[4] = {o01.x + yv * wo.x, o01.y + yv * wo.y, o23.x + yv * wo.z, o23.y + yv * wo.w};
    float cold[4] = {cc.x, cc.y, cc.z, cc.w};
    float cn[4], hn[4];
#pragma unroll
    for (int k = 0; k < 4; k++) {
      cn[k] = sigmoidf_(gf[k]) * cold[k] + sigmoidf_(gi[k]) * tanhf_(gg[k]);
      hn[k] = sigmoidf_(go[k]) * tanhf_(cn[k]);
    }
    *(float4*)(c0 + b * H + j) = (float4){cn[0], cn[1], cn[2], cn[3]};
    ushort4 hv;
    hv.x = __half_as_ushort(__float2half(hn[0]));
    hv.y = __half_as_ushort(__float2half(hn[1]));
    hv.z = __half_as_ushort(__float2half(hn[2]));
    hv.w = __half_as_ushort(__float2half(hn[3]));
    *(ushort4*)(h0 + b * H + j) = hv;
    if (j == 0) {
      if (tPrev >= 0) out[b * T + tPrev] = yv;
      yB[b] = bro[0];   // re-init accumulator for this step's fused readout
    }
  }
}

// prelude: Gh[0][l] = fp16(x) @ Wh[l]^T + bias[l], l = 0..3 (l=4 done by dual(l=2,t=0))
__global__ __launch_bounds__(256) void k_init_gh(
    const __half* __restrict__ hb, const __half* __restrict__ WhbBase,
    __half* __restrict__ GhBase, const float* __restrict__ biasBase)
{
  __shared__ __half sh[SH_HALFS];
  const int t = threadIdx.x;
  const int jb = blockIdx.x * 32;
  const int m0 = blockIdx.y * 128;
  const int l = blockIdx.z;
  f32x4 acc[4][4];
#pragma unroll
  for (int a = 0; a < 4; a++)
#pragma unroll
    for (int b = 0; b < 4; b++) acc[a][b] = (f32x4){0.f, 0.f, 0.f, 0.f};
  gemm_async(hb + l * BSH, WhbBase + (long long)l * GH, m0, jb, sh, t, acc);
  epilogue_store(acc, GhBase + (long long)l * BSG, biasBase + l * G, m0, jb, t);
}

__global__ void k_tail(const float* __restrict__ yF, float* __restrict__ out) {
  int b = threadIdx.x + blockIdx.x * blockDim.x;
  if (b < BS) out[b * T + (T - 1)] = yF[b];
}

extern "C" void kernel_launch(void* const* d_in, const int* in_sizes, int n_in,
                              void* d_out, int out_size, void* d_ws, size_t ws_size,
                              hipStream_t stream) {
  const float* x    = (const float*)d_in[0];
  const float* Wih0 = (const float*)d_in[1];
  const float* Wxf  = (const float*)d_in[2];
  const float* Whf  = (const float*)d_in[3];
  const float* bih  = (const float*)d_in[4];
  const float* bhh  = (const float*)d_in[5];
  const float* Wro  = (const float*)d_in[6];
  const float* bro  = (const float*)d_in[7];
  float* out = (float*)d_out;

  char* ws = (char*)d_ws;
  __half* Whb  = (__half*)(ws);                     // 41,943,040 B
  __half* Wxb  = (__half*)(ws + 41943040LL);        // 33,554,432 B
  __half* hbuf = (__half*)(ws + 75497472LL);        // 5,242,880 B
  float*  c    = (float*)(ws + 80740352LL);         // 10,485,760 B
  __half* Ghb  = (__half*)(ws + 91226112LL);        // 20,971,520 B
  float*  bias = (float*)(ws + 112197632LL);        // 81,920 B
  float*  y0   = (float*)(ws + 112279552LL);        // 2,048 B
  float*  y1   = (float*)(ws + 112281600LL);        // 2,048 B

  k_convert<<<2048, 256, 0, stream>>>(Whf, Wxf, Whb, Wxb);
  k_bias_y<<<80, 256, 0, stream>>>(bih, bhh, bias, y0, y1);
  k_init<<<2048, 256, 0, stream>>>(x, hbuf, c);
  k_init_gh<<<dim3(32, 4, 4), 256, 0, stream>>>(hbuf, Whb, Ghb, bias);

  for (int tst = 0; tst < T; ++tst) {
    float* yA = (tst & 1) ? y1 : y0;
    float* yB = (tst & 1) ? y0 : y1;
    k_head<<<128, 256, 0, stream>>>(Ghb, Wih0, yA, yB, bro, c, hbuf, out, tst - 1);
    for (int l = 1; l < LL; l++) {
      dim3 grid(32, 4, (l == 2) ? 3 : 2);
      k_dual<<<grid, 256, 0, stream>>>(
          hbuf + (l - 1) * BSH,
          Wxb + (long long)(l - 1) * GH,
          Whb + (long long)(l - 1) * GH,
          Ghb + l * BSG,
          Ghb + (l - 1) * BSG,
          bias + (l - 1) * G,
          c + l * BSH,
          hbuf + l * BSH,
          (l == 4) ? Wro : nullptr,
          (l == 4) ? yB : nullptr,
          hbuf + 4 * BSH,            // A2: h[t-1][4] (only used when z==2)
          Whb + 4LL * GH,
          Ghb + 4 * BSG,
          bias + 4 * G);
    }
  }
  k_tail<<<1, 512, 0, stream>>>(y0, out);  // y[127] accumulated into y0 (t=127 -> yB=y0)
}

// Round 3
// 9300.056 us; speedup vs baseline: 1.3305x; 1.3305x over previous
//
#include <hip/hip_runtime.h>
#include <hip/hip_fp16.h>

#define LL 5
#define H 1024
#define G 4096   // 4*H
#define T 128
#define BS 512
#define BSH (BS * H)
#define BSG (BS * G)
#define GH  (G * H)

typedef _Float16 f16x8 __attribute__((ext_vector_type(8)));
typedef float f32x4 __attribute__((ext_vector_type(4)));

__device__ __forceinline__ float sigmoidf_(float x) { return 1.f / (1.f + __expf(-x)); }
__device__ __forceinline__ float tanhf_(float x) { return 2.f / (1.f + __expf(-2.f * x)) - 1.f; }

// async 16B global->LDS (DMA, no VGPR roundtrip). LDS dest = wave-uniform base + lane*16.
__device__ __forceinline__ void gll16(const void* g, void* l) {
  __builtin_amdgcn_global_load_lds(
      (const __attribute__((address_space(1))) void*)g,
      (__attribute__((address_space(3))) void*)l, 16, 0, 0);
}

// counted-vmcnt + raw barrier (T4): loads stay in flight across barriers.
#define VMW(N) asm volatile("s_waitcnt vmcnt(" #N ")" ::: "memory")
#define SBAR() asm volatile("s_barrier" ::: "memory")

// ================= prelude kernels =================

__global__ void k_convert(const float* __restrict__ Whf, const float* __restrict__ Wxf,
                          __half* __restrict__ Whb, __half* __restrict__ Wxb) {
  const long long n1 = (long long)LL * GH / 4;
  const long long n2 = (long long)(LL - 1) * GH / 4;
  long long i = (long long)blockIdx.x * blockDim.x + threadIdx.x;
  long long stride = (long long)gridDim.x * blockDim.x;
  for (long long v = i; v < n1 + n2; v += stride) {
    const float4* src; __half* dst; long long idx;
    if (v < n1) { src = (const float4*)Whf; dst = Whb; idx = v; }
    else        { src = (const float4*)Wxf; dst = Wxb; idx = v - n1; }
    float4 f = src[idx];
    ushort4 u;
    u.x = __half_as_ushort(__float2half(f.x));
    u.y = __half_as_ushort(__float2half(f.y));
    u.z = __half_as_ushort(__float2half(f.z));
    u.w = __half_as_ushort(__float2half(f.w));
    ((ushort4*)dst)[idx] = u;
  }
}

__global__ void k_bias_y(const float* __restrict__ bih, const float* __restrict__ bhh,
                         float* __restrict__ bias, float* __restrict__ y0,
                         float* __restrict__ y1) {
  int i = blockIdx.x * blockDim.x + threadIdx.x;
  if (i < LL * G) bias[i] = bih[i] + bhh[i];
  if (i < BS) { y0[i] = 0.f; y1[i] = 0.f; }
}

__global__ void k_init(const float* __restrict__ x, __half* __restrict__ hbuf,
                       float* __restrict__ c) {
  int i = blockIdx.x * blockDim.x + threadIdx.x;
  if (i >= BS * H) return;
  float v = x[i];
  __half hb = __float2half(v);
  for (int l = 0; l < LL; l++) {
    hbuf[(long long)l * BSH + i] = hb;
    c[(long long)l * BSH + i] = v;
  }
}

// ================= GEMM core (async, dbuf, XOR-swizzled LDS, counted vmcnt) =========
// C(64 x 128) = A(64 rows x K=1024) @ W(128 rows x 1024)^T, W rows = 4 gates x 32 j.
// 256 threads = 4 waves; wave tile 32m x 64n; nt == gate so each lane holds i,f,g,o.
// LDS: 2 x (A 4096 halfs + B 8192 halfs) = 48 KB. Chunk (16B=8 halfs) at slot
// s within row r holds global chunk s ^ (r&7)  -> frag reads are 2-way max (free).
// K-loop: {stage(next); vmcnt(6); barrier; compute(cur); barrier} — next tile's 6
// loads/lane remain in flight across both barriers (no vmcnt(0) drain in the loop).

#define SH_HALFS 24576

__device__ __forceinline__ void stage_tile(const __half* __restrict__ A,
                                           const __half* __restrict__ W,
                                           int m0, int jb, int kb,
                                           __half* aB, __half* bB,
                                           int wave, int lane) {
  const int i8 = lane >> 3;          // row within 8-row group
  const int j8 = lane & 7;           // LDS slot chunk within row
  const int kch = j8 ^ i8;           // swizzled source chunk
#pragma unroll
  for (int s = 0; s < 2; s++) {      // A: 8 calls of 8 rows, this wave does 2
    int c = wave * 2 + s;
    int row = c * 8 + i8;
    gll16(A + (m0 + row) * H + kb + kch * 8, aB + c * 512);
  }
#pragma unroll
  for (int s = 0; s < 4; s++) {      // B: 16 calls of 8 rows, this wave does 4
    int c = wave * 4 + s;
    int row = c * 8 + i8;                          // 0..127
    int grow = (row >> 5) * H + jb + (row & 31);   // gate*H + j
    gll16(W + grow * H + kb + kch * 8, bB + c * 512);
  }
}

__device__ __forceinline__ void compute_tile(const __half* aB, const __half* bB,
                                             int wave, int lane, f32x4 acc[2][4]) {
  const int quad = lane >> 4, col = lane & 15;
  const int wm = wave >> 1, wn = wave & 1;
  const int sw = col & 7;
#pragma unroll
  for (int ks = 0; ks < 2; ks++) {
    const int kc = ks * 4 + quad;
    const int kcs = kc ^ sw;
    f16x8 af[2], bf[4];
#pragma unroll
    for (int mt = 0; mt < 2; mt++) {
      int r = wm * 32 + mt * 16 + col;
      af[mt] = *(const f16x8*)(aB + ((r << 3) + kcs) * 8);
    }
#pragma unroll
    for (int nt = 0; nt < 4; nt++) {
      int n = nt * 32 + wn * 16 + col;
      bf[nt] = *(const f16x8*)(bB + ((n << 3) + kcs) * 8);
    }
#pragma unroll
    for (int mt = 0; mt < 2; mt++)
#pragma unroll
      for (int nt = 0; nt < 4; nt++)
        acc[mt][nt] = __builtin_amdgcn_mfma_f32_16x16x32_f16(af[mt], bf[nt], acc[mt][nt], 0, 0, 0);
  }
}

__device__ __forceinline__ void gemm_async(const __half* __restrict__ A,
                                           const __half* __restrict__ W,
                                           int m0, int jb, __half* sh, int t,
                                           f32x4 acc[2][4]) {
  const int wave = t >> 6, lane = t & 63;
  stage_tile(A, W, m0, jb, 0, sh, sh + 4096, wave, lane);   // 6 loads in flight
  for (int it = 0; it < 15; ++it) {
    const int cur = it & 1;
    // issue next tile into the other buffer (its readers finished at prev trailing barrier)
    stage_tile(A, W, m0, jb, (it + 1) * 64,
               sh + (cur ? 0 : 12288), sh + (cur ? 4096 : 16384), wave, lane);
    VMW(6);   // current tile's 6 loads retired; next tile's 6 stay in flight
    SBAR();
    compute_tile(sh + (cur ? 12288 : 0), sh + (cur ? 16384 : 4096), wave, lane, acc);
    SBAR();   // all readers of buf[cur] done -> next iter may overwrite it
  }
  VMW(0);     // last tile (it=15, cur=1): drain its 6 loads
  SBAR();
  compute_tile(sh + 12288, sh + 16384, wave, lane, acc);
}

__device__ __forceinline__ void epilogue_store(f32x4 acc[2][4], __half* __restrict__ Ghout,
                                               const float* __restrict__ biasS,
                                               int m0, int jb, int t) {
  const int lane = t & 63, wave = t >> 6;
  const int quad = lane >> 4, col = lane & 15;
  const int wm = wave >> 1, wn = wave & 1;
  const int j = jb + wn * 16 + col;
  float bs[4];
#pragma unroll
  for (int nt = 0; nt < 4; nt++) bs[nt] = biasS[nt * H + j];
#pragma unroll
  for (int mt = 0; mt < 2; mt++)
#pragma unroll
    for (int nt = 0; nt < 4; nt++)
#pragma unroll
      for (int r = 0; r < 4; r++) {
        int b = m0 + wm * 32 + mt * 16 + quad * 4 + r;
        Ghout[b * G + nt * H + j] = __float2half(acc[mt][nt][r] + bs[nt]);
      }
}

__device__ __forceinline__ void epilogue_cell(f32x4 acc[2][4],
                                              const __half* __restrict__ Ghin,
                                              float* __restrict__ c, __half* __restrict__ hout,
                                              int m0, int jb, int t,
                                              const float* __restrict__ Wro,
                                              float* __restrict__ yAcc, float* red) {
  const int lane = t & 63, wave = t >> 6;
  const int quad = lane >> 4, col = lane & 15;
  const int wm = wave >> 1, wn = wave & 1;
  const int j = jb + wn * 16 + col;
  const float wj = Wro ? Wro[j] : 0.f;
#pragma unroll
  for (int mt = 0; mt < 2; mt++)
#pragma unroll
    for (int r = 0; r < 4; r++) {
      int row = wm * 32 + mt * 16 + quad * 4 + r;
      int b = m0 + row;
      float gi = acc[mt][0][r] + __half2float(Ghin[b * G + j]);
      float gf = acc[mt][1][r] + __half2float(Ghin[b * G + H + j]);
      float gg = acc[mt][2][r] + __half2float(Ghin[b * G + 2 * H + j]);
      float go = acc[mt][3][r] + __half2float(Ghin[b * G + 3 * H + j]);
      float cold = c[b * H + j];
      float cn = sigmoidf_(gf) * cold + sigmoidf_(gi) * tanhf_(gg);
      float hn = sigmoidf_(go) * tanhf_(cn);
      c[b * H + j] = cn;
      hout[b * H + j] = __float2half(hn);
      if (Wro) red[row * 33 + wn * 16 + col] = hn * wj;  // red fits in buf0 region (dead)
    }
  if (Wro) {  // block-level readout reduction: 32 j-columns -> 1 atomic per row
    __syncthreads();
    if (t < 64) {
      float s = 0.f;
#pragma unroll
      for (int k = 0; k < 32; k++) s += red[t * 33 + k];
      atomicAdd(yAcc + m0 + t, s);
    }
  }
}

// ================= main-loop kernels =================

// z=0: x-GEMM + cell for (t,l): A @ Wc + Ghin -> c, hout  (l==4 also: readout into yAcc)
// z=1: h-GEMM: A @ Ws + biasS -> Ghout   (Gh[t+1][l-1])
// z=2 (only l==2 launch): A2 @ Ws2 + bias2 -> Gh2  (Gh[t][4] from h[t-1][4])
__global__ __launch_bounds__(256) void k_dual(
    const __half* __restrict__ A, const __half* __restrict__ Wc,
    const __half* __restrict__ Ws, const __half* __restrict__ Ghin,
    __half* __restrict__ Ghout, const float* __restrict__ biasS,
    float* __restrict__ c_, __half* __restrict__ hout,
    const float* __restrict__ Wro, float* __restrict__ yAcc,
    const __half* __restrict__ A2, const __half* __restrict__ Ws2,
    __half* __restrict__ Gh2, const float* __restrict__ bias2)
{
  __shared__ __half sh[SH_HALFS];
  const int t = threadIdx.x;
  const int jb = blockIdx.x * 32;
  const int m0 = blockIdx.y * 64;
  f32x4 acc[2][4];
#pragma unroll
  for (int a = 0; a < 2; a++)
#pragma unroll
    for (int b = 0; b < 4; b++) acc[a][b] = (f32x4){0.f, 0.f, 0.f, 0.f};
  if (blockIdx.z == 0) {
    gemm_async(A, Wc, m0, jb, sh, t, acc);
    epilogue_cell(acc, Ghin, c_, hout, m0, jb, t, Wro, yAcc, (float*)sh);
  } else if (blockIdx.z == 1) {
    gemm_async(A, Ws, m0, jb, sh, t, acc);
    epilogue_store(acc, Ghout, biasS, m0, jb, t);
  } else {
    gemm_async(A2, Ws2, m0, jb, sh, t, acc);
    epilogue_store(acc, Gh2, bias2, m0, jb, t);
  }
}

// HEAD: pure elementwise layer-0 cell finalize + y bookkeeping (fast chain link)
__global__ __launch_bounds__(256) void k_head(
    const __half* __restrict__ Gh0, const float* __restrict__ W0,
    const float* __restrict__ yA, float* __restrict__ yB,
    const float* __restrict__ bro, float* __restrict__ c0,
    __half* __restrict__ h0, float* __restrict__ out, int tPrev)
{
  int tid = blockIdx.x * 256 + threadIdx.x;   // 128 blocks -> 32768 threads
  for (int e4 = tid; e4 < BS * (H / 4); e4 += 32768) {
    int b = e4 >> 8;
    int j = (e4 & 255) << 2;
    float yv = yA[b];
    const __half2* p;
    p = (const __half2*)(Gh0 + b * G + j);
    float2 i01 = __half22float2(p[0]), i23 = __half22float2(p[1]);
    p = (const __half2*)(Gh0 + b * G + H + j);
    float2 f01 = __half22float2(p[0]), f23 = __half22float2(p[1]);
    p = (const __half2*)(Gh0 + b * G + 2 * H + j);
    float2 g01 = __half22float2(p[0]), g23 = __half22float2(p[1]);
    p = (const __half2*)(Gh0 + b * G + 3 * H + j);
    float2 o01 = __half22float2(p[0]), o23 = __half22float2(p[1]);
    float4 wi = *(const float4*)(W0 + j);
    float4 wf = *(const float4*)(W0 + H + j);
    float4 wg = *(const float4*)(W0 + 2 * H + j);
    float4 wo = *(const float4*)(W0 + 3 * H + j);
    float4 cc = *(const float4*)(c0 + b * H + j);
    float gi[4] = {i01.x + yv * wi.x, i01.y + yv * wi.y, i23.x + yv * wi.z, i23.y + yv * wi.w};
    float gf[4] = {f01.x + yv * wf.x, f01.y + yv * wf.y, f23.x + yv * wf.z, f23.y + yv * wf.w};
    float gg[4] = {g01.x + yv * wg.x, g01.y + yv * wg.y, g23.x + yv * wg.z, g23.y + yv * wg.w};
    float go[4] = {o01.x + yv * wo.x, o01.y + yv * wo.y, o23.x + yv * wo.z, o23.y + yv * wo.w};
    float cold[4] = {cc.x, cc.y, cc.z, cc.w};
    float cn[4], hn[4];
#pragma unroll
    for (int k = 0; k < 4; k++) {
      cn[k] = sigmoidf_(gf[k]) * cold[k] + sigmoidf_(gi[k]) * tanhf_(gg[k]);
      hn[k] = sigmoidf_(go[k]) * tanhf_(cn[k]);
    }
    *(float4*)(c0 + b * H + j) = (float4){cn[0], cn[1], cn[2], cn[3]};
    ushort4 hv;
    hv.x = __half_as_ushort(__float2half(hn[0]));
    hv.y = __half_as_ushort(__float2half(hn[1]));
    hv.z = __half_as_ushort(__float2half(hn[2]));
    hv.w = __half_as_ushort(__float2half(hn[3]));
    *(ushort4*)(h0 + b * H + j) = hv;
    if (j == 0) {
      if (tPrev >= 0) out[b * T + tPrev] = yv;
      yB[b] = bro[0];   // re-init accumulator for this step's fused readout
    }
  }
}

// prelude: Gh[0][l] = fp16(x) @ Wh[l]^T + bias[l], l = 0..3 (l=4 done by dual(l=2,t=0))
__global__ __launch_bounds__(256) void k_init_gh(
    const __half* __restrict__ hb, const __half* __restrict__ WhbBase,
    __half* __restrict__ GhBase, const float* __restrict__ biasBase)
{
  __shared__ __half sh[SH_HALFS];
  const int t = threadIdx.x;
  const int jb = blockIdx.x * 32;
  const int m0 = blockIdx.y * 64;
  const int l = blockIdx.z;
  f32x4 acc[2][4];
#pragma unroll
  for (int a = 0; a < 2; a++)
#pragma unroll
    for (int b = 0; b < 4; b++) acc[a][b] = (f32x4){0.f, 0.f, 0.f, 0.f};
  gemm_async(hb + l * BSH, WhbBase + (long long)l * GH, m0, jb, sh, t, acc);
  epilogue_store(acc, GhBase + (long long)l * BSG, biasBase + l * G, m0, jb, t);
}

__global__ void k_tail(const float* __restrict__ yF, float* __restrict__ out) {
  int b = threadIdx.x + blockIdx.x * blockDim.x;
  if (b < BS) out[b * T + (T - 1)] = yF[b];
}

extern "C" void kernel_launch(void* const* d_in, const int* in_sizes, int n_in,
                              void* d_out, int out_size, void* d_ws, size_t ws_size,
                              hipStream_t stream) {
  const float* x    = (const float*)d_in[0];
  const float* Wih0 = (const float*)d_in[1];
  const float* Wxf  = (const float*)d_in[2];
  const float* Whf  = (const float*)d_in[3];
  const float* bih  = (const float*)d_in[4];
  const float* bhh  = (const float*)d_in[5];
  const float* Wro  = (const float*)d_in[6];
  const float* bro  = (const float*)d_in[7];
  float* out = (float*)d_out;

  char* ws = (char*)d_ws;
  __half* Whb  = (__half*)(ws);                     // 41,943,040 B
  __half* Wxb  = (__half*)(ws + 41943040LL);        // 33,554,432 B
  __half* hbuf = (__half*)(ws + 75497472LL);        // 5,242,880 B
  float*  c    = (float*)(ws + 80740352LL);         // 10,485,760 B
  __half* Ghb  = (__half*)(ws + 91226112LL);        // 20,971,520 B
  float*  bias = (float*)(ws + 112197632LL);        // 81,920 B
  float*  y0   = (float*)(ws + 112279552LL);        // 2,048 B
  float*  y1   = (float*)(ws + 112281600LL);        // 2,048 B

  k_convert<<<2048, 256, 0, stream>>>(Whf, Wxf, Whb, Wxb);
  k_bias_y<<<80, 256, 0, stream>>>(bih, bhh, bias, y0, y1);
  k_init<<<2048, 256, 0, stream>>>(x, hbuf, c);
  k_init_gh<<<dim3(32, 8, 4), 256, 0, stream>>>(hbuf, Whb, Ghb, bias);

  for (int tst = 0; tst < T; ++tst) {
    float* yA = (tst & 1) ? y1 : y0;
    float* yB = (tst & 1) ? y0 : y1;
    k_head<<<128, 256, 0, stream>>>(Ghb, Wih0, yA, yB, bro, c, hbuf, out, tst - 1);
    for (int l = 1; l < LL; l++) {
      dim3 grid(32, 8, (l == 2) ? 3 : 2);
      k_dual<<<grid, 256, 0, stream>>>(
          hbuf + (l - 1) * BSH,
          Wxb + (long long)(l - 1) * GH,
          Whb + (long long)(l - 1) * GH,
          Ghb + l * BSG,
          Ghb + (l - 1) * BSG,
          bias + (l - 1) * G,
          c + l * BSH,
          hbuf + l * BSH,
          (l == 4) ? Wro : nullptr,
          (l == 4) ? yB : nullptr,
          hbuf + 4 * BSH,            // A2: h[t-1][4] (only used when z==2)
          Whb + 4LL * GH,
          Ghb + 4 * BSG,
          bias + 4 * G);
    }
  }
  k_tail<<<1, 512, 0, stream>>>(y0, out);  // y[127] accumulated into y0 (t=127 -> yB=y0)
}